// Round 9
// baseline (770.122 us; speedup 1.0000x reference)
//
#include <hip/hip_runtime.h>

#define B_  2
#define C_  256
#define S_  6272
#define P_  128
#define NS_ 5
#define KS_ 7
#define KCH_ 896
#define EPS_ 1e-5f
#define TPAD 264

typedef __attribute__((ext_vector_type(8))) short short8;
typedef __attribute__((ext_vector_type(4))) float f32x4;

__device__ __forceinline__ ushort f2bf(float f) {
    union { float f; unsigned u; } v; v.f = f;
    unsigned r = v.u + 0x7fffu + ((v.u >> 16) & 1u);
    return (ushort)(r >> 16);
}
__device__ __forceinline__ float bf2f(ushort h) {
    union { unsigned u; float f; } v; v.u = ((unsigned)h) << 16;
    return v.f;
}

// async global->LDS, 16 bytes per lane; lds dest = wave-uniform base + lane*16
__device__ __forceinline__ void gload16(const ushort* g, ushort* lds) {
    __builtin_amdgcn_global_load_lds(
        (const __attribute__((address_space(1))) void*)g,
        (__attribute__((address_space(3))) void*)lds, 16, 0, 0);
}

// ---------------------------------------------------------------------------
// Weight conversion: Wtp=[Wt;Wp] bf16 [2P,C]; Wg bf16; cat[st][c][k]=[W1|W2]
// (K=256); zero BN stat accumulators. grid: 1280 x 256
// ---------------------------------------------------------------------------
__global__ void k_convert_weights(const float* __restrict__ Wt, const float* __restrict__ Wp,
                                  const float* __restrict__ Wg, const float* __restrict__ W1,
                                  const float* __restrict__ W2,
                                  ushort* __restrict__ Wtpb,
                                  ushort* __restrict__ Wgb, ushort* __restrict__ catb,
                                  float* __restrict__ statb) {
    int i = blockIdx.x * 256 + threadIdx.x;
    const int nWtp = 2 * P_ * C_;        // 65536
    const int nWg  = NS_ * P_ * C_;      // 163840
    const int nCat = NS_ * C_ * 2 * P_;  // 327680
    if (i < nWtp) {
        int c = i & (C_ - 1), row = i >> 8;
        float v = (row < P_) ? Wt[row * C_ + c] : Wp[(row - P_) * C_ + c];
        Wtpb[i] = f2bf(v);
    }
    if (i < nWg) { Wgb[i] = f2bf(Wg[i]); }
    if (i < nCat) {
        int k  = i & 255;
        int c  = (i >> 8) & (C_ - 1);
        int st = i >> 16;
        float v = (k < P_) ? W1[((size_t)st * C_ + c) * P_ + k]
                           : W2[((size_t)st * C_ + c) * P_ + (k - P_)];
        catb[i] = f2bf(v);
    }
    if (i < NS_ * 2 * C_) statb[i] = 0.f;
}

// ---------------------------------------------------------------------------
// init: out = x (fp32 copy), xb_sc[b][s][c] = bf16(x[b][c][s])
// LDS-tiled transpose: 64 s x 256 c per block. grid: B_*98 x 256
// ---------------------------------------------------------------------------
__global__ __launch_bounds__(256)
void k_init_x(const float* __restrict__ x, float* __restrict__ out,
              ushort* __restrict__ xb_sc) {
    __shared__ ushort tl[64][TPAD];
    const int bs = blockIdx.x;
    const int b = bs / 98, s0 = (bs - b * 98) * 64;
    const int tid = threadIdx.x, sl = tid & 63, cg = tid >> 6;
    #pragma unroll 4
    for (int it = 0; it < 64; ++it) {
        int c = it * 4 + cg;
        long idx = ((long)b * C_ + c) * S_ + s0 + sl;
        float v = x[idx];
        out[idx] = v;
        tl[sl][c] = f2bf(v);
    }
    __syncthreads();
    ushort* xs = xb_sc + ((long)b * S_ + s0) * C_;
    #pragma unroll
    for (int u0 = 0; u0 < 2048; u0 += 256) {
        int u = u0 + tid;
        int s = u >> 5, c8 = (u & 31) << 3;
        short8 w = *(const short8*)&tl[s][c8];
        *(short8*)&xs[(long)s * C_ + c8] = w;
    }
}

// ---------------------------------------------------------------------------
// NT GEMM: Out[M,N] = A[M,K] * B[N,K]^T   (both operands K-contiguous bf16)
// MODE 0: bf16 Out (LDS-repacked coalesced short8 stores)
// MODE 1: MODE 0 + bf16 OutT[N,M] (coalesced 32B runs via LDS column reads)
// MODE 3: fp32 Out + per-channel (row) BN stat atomics into Stat[0:M],[M:2M]
// 128x128 tile, 4 waves, BK=64 (32 MFMA per barrier interval: covers ~900cy
// HBM latency at 8 waves/CU), 2-phase LDS double-buffer via global_load_lds.
// 3-bit XOR slot swizzle slot=chunk^(row&7), applied BOTH sides (involution);
// ds_read_b128 lands at 8 accesses/bank = structural floor.
// ---------------------------------------------------------------------------
template <int MODE>
__global__ __launch_bounds__(256, 2)
void k_gemm(const ushort* __restrict__ A, const ushort* __restrict__ Bm,
            void* __restrict__ Out, ushort* __restrict__ OutT, float* __restrict__ Stat,
            int M, int N, int K, int lda, int ldb, int ldo, int ldot,
            long sA, long sB, long sOb, long sOch, long sOT, int nks, int kch) {
    const int z = blockIdx.z;
    const int b = z / nks, ch = z - b * nks;
    A  += (long)b * sA;
    Bm += (long)b * sB;
    const int k0 = ch * kch;

    const int bm = blockIdx.x * 128, bn = blockIdx.y * 128;

    __shared__ ushort Al[2][128][64];
    __shared__ ushort Bl[2][128][64];
    __shared__ ushort ep[32][130];   // epilogue repack (pad 130: col reads 1 bank/row)

    const int tid = threadIdx.x, lane = tid & 63, wid = tid >> 6;
    const int wr = (wid >> 1) * 64, wc = (wid & 1) * 64;
    const int r16 = lane & 15, kg = lane >> 4;

    // staging geometry: one gload16 covers 8 rows x 64B; lane -> row lane>>3,
    // 16B chunk lane&7; global chunk = lds_slot ^ (row&7)
    const int st_row8 = lane >> 3;                       // 0..7
    const int st_goff = ((lane & 7) ^ st_row8) << 3;     // swizzled elem offset
    // fragment read slots (elem offsets) for the two K=32 halves
    const int swA0 = ((kg ^ (r16 & 7)) << 3);            // k 0..31  (chunks 0..3)
    const int swA1 = (((kg + 4) ^ (r16 & 7)) << 3);      // k 32..63 (chunks 4..7)

    f32x4 acc[4][4];
    #pragma unroll
    for (int i = 0; i < 4; ++i)
        #pragma unroll
        for (int j = 0; j < 4; ++j)
            acc[i][j] = (f32x4){0.f, 0.f, 0.f, 0.f};

    auto stage = [&](int kk, int buf) {
        #pragma unroll
        for (int i = 0; i < 4; ++i) {
            int r = wid * 32 + i * 8;
            gload16(A + (long)(bm + r + st_row8) * lda + kk + st_goff, &Al[buf][r][0]);
        }
        #pragma unroll
        for (int i = 0; i < 4; ++i) {
            int r = wid * 32 + i * 8;
            gload16(Bm + (long)(bn + r + st_row8) * ldb + kk + st_goff, &Bl[buf][r][0]);
        }
    };
    auto compute = [&](int buf) {
        #pragma unroll
        for (int h = 0; h < 2; ++h) {
            const int sw = h ? swA1 : swA0;
            short8 af[4], bfv[4];
            #pragma unroll
            for (int i = 0; i < 4; ++i)
                af[i] = *(const short8*)&Al[buf][wr + i * 16 + r16][sw];
            #pragma unroll
            for (int j = 0; j < 4; ++j)
                bfv[j] = *(const short8*)&Bl[buf][wc + j * 16 + r16][sw];
            #pragma unroll
            for (int i = 0; i < 4; ++i)
                #pragma unroll
                for (int j = 0; j < 4; ++j)
                    acc[i][j] = __builtin_amdgcn_mfma_f32_16x16x32_bf16(af[i], bfv[j], acc[i][j], 0, 0, 0);
        }
    };

    const int nt = kch >> 6;                 // BK=64 steps
    stage(k0, 0);
    __syncthreads();
    int cur = 0;
    for (int t = 0; t < nt - 1; ++t) {
        stage(k0 + (t + 1) * 64, cur ^ 1);   // prefetch next (drains at barrier)
        compute(cur);
        __syncthreads();
        cur ^= 1;
    }
    compute(cur);

    const int orow0 = bm + wr + kg * 4;
    const int ocol0 = bn + wc + r16;
    if (MODE == 3) {
        float* O = (float*)Out + (long)b * sOb + (long)ch * sOch;
        #pragma unroll
        for (int i = 0; i < 4; ++i)
            #pragma unroll
            for (int j = 0; j < 4; ++j)
                #pragma unroll
                for (int q = 0; q < 4; ++q)
                    O[(long)(orow0 + i * 16 + q) * ldo + (ocol0 + j * 16)] = acc[i][j][q];
        #pragma unroll
        for (int i = 0; i < 4; ++i)
            #pragma unroll
            for (int q = 0; q < 4; ++q) {
                float s1 = acc[i][0][q] + acc[i][1][q] + acc[i][2][q] + acc[i][3][q];
                float s2 = acc[i][0][q] * acc[i][0][q] + acc[i][1][q] * acc[i][1][q]
                         + acc[i][2][q] * acc[i][2][q] + acc[i][3][q] * acc[i][3][q];
                #pragma unroll
                for (int off = 1; off < 16; off <<= 1) {
                    s1 += __shfl_xor(s1, off);
                    s2 += __shfl_xor(s2, off);
                }
                if (r16 == 0) {
                    atomicAdd(&Stat[orow0 + i * 16 + q], s1);
                    atomicAdd(&Stat[M + orow0 + i * 16 + q], s2);
                }
            }
    } else {
        // LDS-repacked coalesced epilogue (modes 0/1)
        ushort* O = (ushort*)Out + (long)b * sOb + (long)ch * sOch;
        ushort* OT = (MODE == 1) ? (OutT + (long)b * sOT) : nullptr;
        const int wrH = wid >> 1;               // which 64-row half this wave owns
        #pragma unroll
        for (int i = 0; i < 4; ++i) {
            __syncthreads();                    // prior iteration's reads done
            #pragma unroll
            for (int j = 0; j < 4; ++j)
                #pragma unroll
                for (int q = 0; q < 4; ++q)
                    ep[wrH * 16 + kg * 4 + q][wc + j * 16 + r16] = f2bf(acc[i][j][q]);
            __syncthreads();
            // row-major stores: 32 rows x 128 cols, short8 per lane
            #pragma unroll
            for (int p = 0; p < 2; ++p) {
                int r = p * 16 + (tid >> 4);            // 0..31
                int c8 = (tid & 15) << 3;               // 0..120
                short8 w = *(const short8*)&ep[r][c8];
                int grow = bm + (r >> 4) * 64 + i * 16 + (r & 15);
                *(short8*)&O[(long)grow * ldo + bn + c8] = w;
            }
            if (MODE == 1) {
                // transposed stores: thread -> (col c, half h); 16 m-elems = 32 B
                int c = tid >> 1, h = tid & 1;
                short8 w0, w1;
                #pragma unroll
                for (int r = 0; r < 8; ++r) w0[r] = (short)ep[h * 16 + r][c];
                #pragma unroll
                for (int r = 0; r < 8; ++r) w1[r] = (short)ep[h * 16 + 8 + r][c];
                long obase = (long)(bn + c) * ldot + bm + h * 64 + i * 16;
                *(short8*)&OT[obase] = w0;
                *(short8*)&OT[obase + 8] = w1;
            }
        }
    }
}

// ---------------------------------------------------------------------------
// In-place row softmax over bf16 scores: B_*S_ rows of length S_ (vectorized)
// ---------------------------------------------------------------------------
__global__ __launch_bounds__(256)
void k_softmax(ushort* __restrict__ att) {
    long row = blockIdx.x;
    ushort* r = att + row * (long)S_;
    const int tid = threadIdx.x;
    __shared__ float red1[4];
    __shared__ float red2[4];
    const bool tail = tid < 16;

    short8 u0 = *(const short8*)&r[(0 * 256 + tid) * 8];
    short8 u1 = *(const short8*)&r[(1 * 256 + tid) * 8];
    short8 u2 = *(const short8*)&r[(2 * 256 + tid) * 8];
    short8 u3 = tail ? *(const short8*)&r[(768 + tid) * 8] : short8{0,0,0,0,0,0,0,0};

    float v[32];
    #pragma unroll
    for (int j = 0; j < 8; ++j) {
        v[j]      = bf2f((ushort)u0[j]);
        v[8 + j]  = bf2f((ushort)u1[j]);
        v[16 + j] = bf2f((ushort)u2[j]);
        v[24 + j] = tail ? bf2f((ushort)u3[j]) : -1e30f;
    }
    float mx = -1e30f;
    #pragma unroll
    for (int j = 0; j < 32; ++j) mx = fmaxf(mx, v[j]);
    #pragma unroll
    for (int off = 32; off; off >>= 1) mx = fmaxf(mx, __shfl_xor(mx, off));
    if ((tid & 63) == 0) red1[tid >> 6] = mx;
    __syncthreads();
    mx = fmaxf(fmaxf(red1[0], red1[1]), fmaxf(red1[2], red1[3]));

    float sum = 0.f;
    #pragma unroll
    for (int j = 0; j < 32; ++j) {
        float e = __expf(v[j] - mx);
        v[j] = e;
        sum += e;
    }
    #pragma unroll
    for (int off = 32; off; off >>= 1) sum += __shfl_xor(sum, off);
    if ((tid & 63) == 0) red2[tid >> 6] = sum;
    __syncthreads();
    sum = red2[0] + red2[1] + red2[2] + red2[3];
    float inv = 1.f / sum;

    short8 w0, w1, w2, w3;
    #pragma unroll
    for (int j = 0; j < 8; ++j) {
        w0[j] = (short)f2bf(v[j] * inv);
        w1[j] = (short)f2bf(v[8 + j] * inv);
        w2[j] = (short)f2bf(v[16 + j] * inv);
        w3[j] = (short)f2bf(v[24 + j] * inv);
    }
    *(short8*)&r[(0 * 256 + tid) * 8] = w0;
    *(short8*)&r[(1 * 256 + tid) * 8] = w1;
    *(short8*)&r[(2 * 256 + tid) * 8] = w2;
    if (tail) *(short8*)&r[(768 + tid) * 8] = w3;
}

// ---------------------------------------------------------------------------
// Reduce bf16 split-K chunks -> BcatT[b][s][128+p]; split: [b][ch][s][p] bf16
// grid: 784 x 256 (thread per (b,s,p8))
// ---------------------------------------------------------------------------
__global__ void k_reduce_split(const ushort* __restrict__ splitb, ushort* __restrict__ BcatT) {
    long i = (long)blockIdx.x * 256 + threadIdx.x;   // over B_*S_*(P_/8)
    if (i >= (long)B_ * S_ * (P_ / 8)) return;
    int p8 = (int)(i & (P_ / 8 - 1));
    long sp = i >> 4;
    int b = (int)(sp / S_);
    long s = sp - (long)b * S_;
    const ushort* base = splitb + ((long)b * KS_ * S_ + s) * P_ + p8 * 8;
    float acc[8] = {0.f, 0.f, 0.f, 0.f, 0.f, 0.f, 0.f, 0.f};
    #pragma unroll
    for (int ch = 0; ch < KS_; ++ch) {
        short8 u = *(const short8*)&base[(long)ch * S_ * P_];
        #pragma unroll
        for (int j = 0; j < 8; ++j) acc[j] += bf2f((ushort)u[j]);
    }
    short8 w;
    #pragma unroll
    for (int j = 0; j < 8; ++j) w[j] = (short)f2bf(acc[j]);
    *(short8*)&BcatT[((long)b * S_ + s) * 256 + 128 + p8 * 8] = w;
}

// ---------------------------------------------------------------------------
// BN apply + residual: out += BN(y) using fused Stat accumulators;
// LDS-tiled transpose for xb_sc writes. grid: B_*98 x 256
// ---------------------------------------------------------------------------
__global__ __launch_bounds__(256)
void k_bn_apply(const float* __restrict__ y, const float* __restrict__ Stat,
                const float* __restrict__ gamma, const float* __restrict__ beta,
                float* __restrict__ out, ushort* __restrict__ xb_sc) {
    __shared__ ushort tl[64][TPAD];
    const int bs = blockIdx.x;
    const int b = bs / 98, s0 = (bs - b * 98) * 64;
    const int tid = threadIdx.x, sl = tid & 63, cg = tid >> 6;
    const float invn = 1.f / (float)(B_ * S_);
    #pragma unroll 4
    for (int it = 0; it < 64; ++it) {
        int c = it * 4 + cg;
        float m = Stat[c] * invn;
        float var = Stat[C_ + c] * invn - m * m;
        float rs = rsqrtf(var + EPS_);
        float sc = rs * gamma[c];
        float sh = beta[c] - m * sc;
        long idx = ((long)b * C_ + c) * S_ + s0 + sl;
        float v = out[idx] + y[idx] * sc + sh;
        out[idx] = v;
        tl[sl][c] = f2bf(v);
    }
    __syncthreads();
    ushort* xs = xb_sc + ((long)b * S_ + s0) * C_;
    #pragma unroll
    for (int u0 = 0; u0 < 2048; u0 += 256) {
        int u = u0 + tid;
        int s = u >> 5, c8 = (u & 31) << 3;
        short8 w = *(const short8*)&tl[s][c8];
        *(short8*)&xs[(long)s * C_ + c8] = w;
    }
}

// ---------------------------------------------------------------------------
extern "C" void kernel_launch(void* const* d_in, const int* in_sizes, int n_in,
                              void* d_out, int out_size, void* d_ws, size_t ws_size,
                              hipStream_t stream) {
    const float* x     = (const float*)d_in[0];
    const float* Wt    = (const float*)d_in[1];
    const float* Wp    = (const float*)d_in[2];
    const float* Wg    = (const float*)d_in[3];
    const float* W1    = (const float*)d_in[4];
    const float* W2    = (const float*)d_in[5];
    const float* gamma = (const float*)d_in[6];
    const float* beta  = (const float*)d_in[7];
    float* out = (float*)d_out;

    char* ws = (char*)d_ws;
    size_t off = 0;
    auto alloc = [&](size_t bytes) -> void* {
        void* p = ws + off;
        off = (off + bytes + 255) & ~(size_t)255;
        return p;
    };
    ushort* att    = (ushort*)alloc((size_t)B_ * S_ * S_ * 2);       // scores/att bf16
    ushort* tpb    = (ushort*)alloc((size_t)B_ * S_ * 256 * 2);      // [s][t | p^T]
    ushort* gTb    = (ushort*)alloc((size_t)B_ * P_ * S_ * 2);       // g^T [P,S]
    ushort* BcatT  = (ushort*)alloc((size_t)B_ * S_ * 256 * 2);      // [s][g | x2pre]
    ushort* xbsc   = (ushort*)alloc((size_t)B_ * S_ * C_ * 2);       // out^T bf16 [S,C]
    float*  y      = (float*)alloc((size_t)B_ * C_ * S_ * 4);        // x1+x2 fp32 [C,S]
    ushort* splitb = (ushort*)alloc((size_t)B_ * KS_ * S_ * P_ * 2); // split-K bf16
    ushort* Wtpb   = (ushort*)alloc((size_t)2 * P_ * C_ * 2);
    ushort* Wgb    = (ushort*)alloc((size_t)NS_ * P_ * C_ * 2);
    ushort* catb   = (ushort*)alloc((size_t)NS_ * C_ * 256 * 2);
    float*  statb  = (float*)alloc((size_t)NS_ * 2 * C_ * 4);
    if (off > ws_size) return;

    dim3 blk(256);

    k_convert_weights<<<1280, 256, 0, stream>>>(Wt, Wp, Wg, W1, W2, Wtpb, Wgb, catb, statb);
    k_init_x<<<B_ * 98, 256, 0, stream>>>(x, out, xbsc);

    // [t | p^T] = NT(xbsc[S,C], Wtp[256,C]) -> tpb [S,256]
    k_gemm<0><<<dim3(S_ / 128, 2, B_), blk, 0, stream>>>(
        xbsc, Wtpb, tpb, nullptr, nullptr, S_, 256, C_, C_, C_, 256, 0,
        (long)S_ * C_, 0, (long)S_ * 256, 0, 0, 1, C_);
    // scores = NT(t[S,P] lda=256, p^T[S,P] ldb=256) -> att [S,S]
    k_gemm<0><<<dim3(S_ / 128, S_ / 128, B_), blk, 0, stream>>>(
        tpb, tpb + 128, att, nullptr, nullptr, S_, S_, P_, 256, 256, S_, 0,
        (long)S_ * 256, (long)S_ * 256, (long)S_ * S_, 0, 0, 1, P_);
    k_softmax<<<B_ * S_, 256, 0, stream>>>(att);

    for (int i = 0; i < NS_; ++i) {
        // g = NT(xbsc, Wg[i]) -> BcatT cols [0,128) (ldo=256) + gTb [P,S]
        k_gemm<1><<<dim3(S_ / 128, 1, B_), blk, 0, stream>>>(
            xbsc, Wgb + (size_t)i * P_ * C_, BcatT, gTb, nullptr,
            S_, P_, C_, C_, C_, 256, S_,
            (long)S_ * C_, 0, (long)S_ * 256, 0, (long)P_ * S_, 1, C_);
        // x2pre(split-K) = NT(att[S,S], gT[P,S]) -> splitb bf16 [b][ch][S][P]
        k_gemm<0><<<dim3(S_ / 128, 1, B_ * KS_), blk, 0, stream>>>(
            att, gTb, splitb, nullptr, nullptr, S_, P_, S_, S_, S_, P_, 0,
            (long)S_ * S_, (long)P_ * S_, (long)KS_ * S_ * P_, (long)S_ * P_, 0, KS_, KCH_);
        k_reduce_split<<<784, 256, 0, stream>>>(splitb, BcatT);
        // y = NT(cat[i][C,256], BcatT[S,256]) -> [C,S] fp32 + BN stat atomics
        k_gemm<3><<<dim3(C_ / 128, S_ / 128, B_), blk, 0, stream>>>(
            catb + (size_t)i * C_ * 256, BcatT, y, nullptr, statb + (size_t)i * 2 * C_,
            C_, S_, 256, 256, 256, S_, 0,
            0, (long)S_ * 256, (long)C_ * S_, 0, 0, 1, 256);
        k_bn_apply<<<B_ * 98, 256, 0, stream>>>(y, statb + (size_t)i * 2 * C_,
                                                gamma + i * C_, beta + i * C_, out, xbsc);
    }
}

// Round 10
// 653.179 us; speedup vs baseline: 1.1790x; 1.1790x over previous
//
#include <hip/hip_runtime.h>

#define B_  2
#define C_  256
#define S_  6272
#define P_  128
#define NS_ 5
#define KS_ 7
#define KCH_ 896
#define EPS_ 1e-5f
#define TPAD 264

typedef __attribute__((ext_vector_type(8))) short short8;
typedef __attribute__((ext_vector_type(4))) float f32x4;

__device__ __forceinline__ ushort f2bf(float f) {
    union { float f; unsigned u; } v; v.f = f;
    unsigned r = v.u + 0x7fffu + ((v.u >> 16) & 1u);
    return (ushort)(r >> 16);
}
__device__ __forceinline__ float bf2f(ushort h) {
    union { unsigned u; float f; } v; v.u = ((unsigned)h) << 16;
    return v.f;
}

// async global->LDS, 16 bytes per lane; lds dest = wave-uniform base + lane*16
__device__ __forceinline__ void gload16(const ushort* g, ushort* lds) {
    __builtin_amdgcn_global_load_lds(
        (const __attribute__((address_space(1))) void*)g,
        (__attribute__((address_space(3))) void*)lds, 16, 0, 0);
}

// ---------------------------------------------------------------------------
// Weight conversion: Wtp=[Wt;Wp] bf16 [2P,C]; Wg bf16; cat[st][c][k]=[W1|W2]
// (K=256); zero BN stat accumulators. grid: 1280 x 256
// ---------------------------------------------------------------------------
__global__ void k_convert_weights(const float* __restrict__ Wt, const float* __restrict__ Wp,
                                  const float* __restrict__ Wg, const float* __restrict__ W1,
                                  const float* __restrict__ W2,
                                  ushort* __restrict__ Wtpb,
                                  ushort* __restrict__ Wgb, ushort* __restrict__ catb,
                                  float* __restrict__ statb) {
    int i = blockIdx.x * 256 + threadIdx.x;
    const int nWtp = 2 * P_ * C_;        // 65536
    const int nWg  = NS_ * P_ * C_;      // 163840
    const int nCat = NS_ * C_ * 2 * P_;  // 327680
    if (i < nWtp) {
        int c = i & (C_ - 1), row = i >> 8;
        float v = (row < P_) ? Wt[row * C_ + c] : Wp[(row - P_) * C_ + c];
        Wtpb[i] = f2bf(v);
    }
    if (i < nWg) { Wgb[i] = f2bf(Wg[i]); }
    if (i < nCat) {
        int k  = i & 255;
        int c  = (i >> 8) & (C_ - 1);
        int st = i >> 16;
        float v = (k < P_) ? W1[((size_t)st * C_ + c) * P_ + k]
                           : W2[((size_t)st * C_ + c) * P_ + (k - P_)];
        catb[i] = f2bf(v);
    }
    if (i < NS_ * 2 * C_) statb[i] = 0.f;
}

// ---------------------------------------------------------------------------
// init: out = x (fp32 copy), xb_sc[b][s][c] = bf16(x[b][c][s])
// LDS-tiled transpose: 64 s x 256 c per block. grid: B_*98 x 256
// ---------------------------------------------------------------------------
__global__ __launch_bounds__(256)
void k_init_x(const float* __restrict__ x, float* __restrict__ out,
              ushort* __restrict__ xb_sc) {
    __shared__ ushort tl[64][TPAD];
    const int bs = blockIdx.x;
    const int b = bs / 98, s0 = (bs - b * 98) * 64;
    const int tid = threadIdx.x, sl = tid & 63, cg = tid >> 6;
    #pragma unroll 4
    for (int it = 0; it < 64; ++it) {
        int c = it * 4 + cg;
        long idx = ((long)b * C_ + c) * S_ + s0 + sl;
        float v = x[idx];
        out[idx] = v;
        tl[sl][c] = f2bf(v);
    }
    __syncthreads();
    ushort* xs = xb_sc + ((long)b * S_ + s0) * C_;
    #pragma unroll
    for (int u0 = 0; u0 < 2048; u0 += 256) {
        int u = u0 + tid;
        int s = u >> 5, c8 = (u & 31) << 3;
        short8 w = *(const short8*)&tl[s][c8];
        *(short8*)&xs[(long)s * C_ + c8] = w;
    }
}

// ---------------------------------------------------------------------------
// NT GEMM: Out[M,N] = A[M,K] * B[N,K]^T   (both operands K-contiguous bf16)
// MODE 0: bf16 Out (LDS-repacked coalesced short8 stores)
// MODE 1: MODE 0 + bf16 OutT[N,M] (coalesced 32B runs via LDS column reads)
// MODE 3: fp32 Out + per-channel (row) BN stat atomics into Stat[0:M],[M:2M]
// TM: M-tile (128 or 64). TM=64 doubles block count for narrow-M GEMMs.
// BK=32, 2-phase LDS double-buffer via global_load_lds; XOR slot swizzle on
// BOTH global source and ds_read (both-sides-or-neither).
// ---------------------------------------------------------------------------
template <int MODE, int TM>
__global__ __launch_bounds__(256, 3)
void k_gemm(const ushort* __restrict__ A, const ushort* __restrict__ Bm,
            void* __restrict__ Out, ushort* __restrict__ OutT, float* __restrict__ Stat,
            int M, int N, int K, int lda, int ldb, int ldo, int ldot,
            long sA, long sB, long sOb, long sOch, long sOT, int nks, int kch) {
    const int z = blockIdx.z;
    const int b = z / nks, ch = z - b * nks;
    A  += (long)b * sA;
    Bm += (long)b * sB;
    const int k0 = ch * kch;

    const int bm = blockIdx.x * TM, bn = blockIdx.y * 128;
    const int NI = TM / 32;          // acc row-frags per wave (4 or 2)
    const int RS = TM / 2;           // wave row span (64 or 32)

    __shared__ ushort Al[2][TM][32];
    __shared__ ushort Bl[2][128][32];
    __shared__ ushort ep[32][130];   // epilogue repack (pad 130: col reads 1 bank/row)

    const int tid = threadIdx.x, lane = tid & 63, wid = tid >> 6;
    const int wr = (wid >> 1) * RS, wc = (wid & 1) * 64;
    const int r16 = lane & 15, kg = lane >> 4;

    // staging geometry: one instr covers 16 rows (lane l -> row l>>2, slot l&3)
    const int st_row = lane >> 2;
    const int st_slot = lane & 3;
    const int st_gk8 = ((st_slot ^ ((st_row >> 1) & 3)) << 3);
    const int sw8 = ((kg ^ ((r16 >> 1) & 3)) << 3);

    f32x4 acc[NI][4];
    #pragma unroll
    for (int i = 0; i < NI; ++i)
        #pragma unroll
        for (int j = 0; j < 4; ++j)
            acc[i][j] = (f32x4){0.f, 0.f, 0.f, 0.f};

    auto stage = [&](int kk, int buf) {
        if (TM == 128) {
            gload16(A + (long)(bm + wid * 32 + st_row) * lda + kk + st_gk8,
                    &Al[buf][wid * 32][0]);
            gload16(A + (long)(bm + wid * 32 + 16 + st_row) * lda + kk + st_gk8,
                    &Al[buf][wid * 32 + 16][0]);
        } else {
            gload16(A + (long)(bm + wid * 16 + st_row) * lda + kk + st_gk8,
                    &Al[buf][wid * 16][0]);
        }
        gload16(Bm + (long)(bn + wid * 32 + st_row) * ldb + kk + st_gk8,
                &Bl[buf][wid * 32][0]);
        gload16(Bm + (long)(bn + wid * 32 + 16 + st_row) * ldb + kk + st_gk8,
                &Bl[buf][wid * 32 + 16][0]);
    };
    auto compute = [&](int buf) {
        short8 af[NI], bfv[4];
        #pragma unroll
        for (int i = 0; i < NI; ++i)
            af[i] = *(const short8*)&Al[buf][wr + i * 16 + r16][sw8];
        #pragma unroll
        for (int j = 0; j < 4; ++j)
            bfv[j] = *(const short8*)&Bl[buf][wc + j * 16 + r16][sw8];
        #pragma unroll
        for (int i = 0; i < NI; ++i)
            #pragma unroll
            for (int j = 0; j < 4; ++j)
                acc[i][j] = __builtin_amdgcn_mfma_f32_16x16x32_bf16(af[i], bfv[j], acc[i][j], 0, 0, 0);
    };

    const int nt = kch >> 5;
    stage(k0, 0);
    __syncthreads();
    int cur = 0;
    for (int t = 0; t < nt - 1; ++t) {
        stage(k0 + (t + 1) * 32, cur ^ 1);
        compute(cur);
        __syncthreads();
        cur ^= 1;
    }
    compute(cur);

    const int orow0 = bm + wr + kg * 4;
    const int ocol0 = bn + wc + r16;
    if (MODE == 3) {
        float* O = (float*)Out + (long)b * sOb + (long)ch * sOch;
        #pragma unroll
        for (int i = 0; i < NI; ++i)
            #pragma unroll
            for (int j = 0; j < 4; ++j)
                #pragma unroll
                for (int q = 0; q < 4; ++q)
                    O[(long)(orow0 + i * 16 + q) * ldo + (ocol0 + j * 16)] = acc[i][j][q];
        #pragma unroll
        for (int i = 0; i < NI; ++i)
            #pragma unroll
            for (int q = 0; q < 4; ++q) {
                float s1 = acc[i][0][q] + acc[i][1][q] + acc[i][2][q] + acc[i][3][q];
                float s2 = acc[i][0][q] * acc[i][0][q] + acc[i][1][q] * acc[i][1][q]
                         + acc[i][2][q] * acc[i][2][q] + acc[i][3][q] * acc[i][3][q];
                #pragma unroll
                for (int off = 1; off < 16; off <<= 1) {
                    s1 += __shfl_xor(s1, off);
                    s2 += __shfl_xor(s2, off);
                }
                if (r16 == 0) {
                    atomicAdd(&Stat[orow0 + i * 16 + q], s1);
                    atomicAdd(&Stat[M + orow0 + i * 16 + q], s2);
                }
            }
    } else {
        // LDS-repacked coalesced epilogue (modes 0/1)
        ushort* O = (ushort*)Out + (long)b * sOb + (long)ch * sOch;
        ushort* OT = (MODE == 1) ? (OutT + (long)b * sOT) : nullptr;
        const int wrH = wid >> 1;               // which row-half this wave owns
        #pragma unroll
        for (int i = 0; i < NI; ++i) {
            __syncthreads();                    // prior iteration's reads done
            #pragma unroll
            for (int j = 0; j < 4; ++j)
                #pragma unroll
                for (int q = 0; q < 4; ++q)
                    ep[wrH * 16 + kg * 4 + q][wc + j * 16 + r16] = f2bf(acc[i][j][q]);
            __syncthreads();
            // row-major stores: 32 rows x 128 cols, short8 per lane
            #pragma unroll
            for (int p = 0; p < 2; ++p) {
                int r = p * 16 + (tid >> 4);            // 0..31
                int c8 = (tid & 15) << 3;               // 0..120
                short8 w = *(const short8*)&ep[r][c8];
                int grow = bm + (r >> 4) * RS + i * 16 + (r & 15);
                *(short8*)&O[(long)grow * ldo + bn + c8] = w;
            }
            if (MODE == 1) {
                // transposed stores: thread -> (col c, half h); 16 m-elems = 32 B
                int c = tid >> 1, h = tid & 1;
                short8 w0, w1;
                #pragma unroll
                for (int r = 0; r < 8; ++r) w0[r] = (short)ep[h * 16 + r][c];
                #pragma unroll
                for (int r = 0; r < 8; ++r) w1[r] = (short)ep[h * 16 + 8 + r][c];
                long obase = (long)(bn + c) * ldot + bm + h * RS + i * 16;
                *(short8*)&OT[obase] = w0;
                *(short8*)&OT[obase + 8] = w1;
            }
        }
    }
}

// ---------------------------------------------------------------------------
// In-place row softmax over bf16 scores: B_*S_ rows of length S_ (vectorized)
// ---------------------------------------------------------------------------
__global__ __launch_bounds__(256)
void k_softmax(ushort* __restrict__ att) {
    long row = blockIdx.x;
    ushort* r = att + row * (long)S_;
    const int tid = threadIdx.x;
    __shared__ float red1[4];
    __shared__ float red2[4];
    const bool tail = tid < 16;

    short8 u0 = *(const short8*)&r[(0 * 256 + tid) * 8];
    short8 u1 = *(const short8*)&r[(1 * 256 + tid) * 8];
    short8 u2 = *(const short8*)&r[(2 * 256 + tid) * 8];
    short8 u3 = tail ? *(const short8*)&r[(768 + tid) * 8] : short8{0,0,0,0,0,0,0,0};

    float v[32];
    #pragma unroll
    for (int j = 0; j < 8; ++j) {
        v[j]      = bf2f((ushort)u0[j]);
        v[8 + j]  = bf2f((ushort)u1[j]);
        v[16 + j] = bf2f((ushort)u2[j]);
        v[24 + j] = tail ? bf2f((ushort)u3[j]) : -1e30f;
    }
    float mx = -1e30f;
    #pragma unroll
    for (int j = 0; j < 32; ++j) mx = fmaxf(mx, v[j]);
    #pragma unroll
    for (int off = 32; off; off >>= 1) mx = fmaxf(mx, __shfl_xor(mx, off));
    if ((tid & 63) == 0) red1[tid >> 6] = mx;
    __syncthreads();
    mx = fmaxf(fmaxf(red1[0], red1[1]), fmaxf(red1[2], red1[3]));

    float sum = 0.f;
    #pragma unroll
    for (int j = 0; j < 32; ++j) {
        float e = __expf(v[j] - mx);
        v[j] = e;
        sum += e;
    }
    #pragma unroll
    for (int off = 32; off; off >>= 1) sum += __shfl_xor(sum, off);
    if ((tid & 63) == 0) red2[tid >> 6] = sum;
    __syncthreads();
    sum = red2[0] + red2[1] + red2[2] + red2[3];
    float inv = 1.f / sum;

    short8 w0, w1, w2, w3;
    #pragma unroll
    for (int j = 0; j < 8; ++j) {
        w0[j] = (short)f2bf(v[j] * inv);
        w1[j] = (short)f2bf(v[8 + j] * inv);
        w2[j] = (short)f2bf(v[16 + j] * inv);
        w3[j] = (short)f2bf(v[24 + j] * inv);
    }
    *(short8*)&r[(0 * 256 + tid) * 8] = w0;
    *(short8*)&r[(1 * 256 + tid) * 8] = w1;
    *(short8*)&r[(2 * 256 + tid) * 8] = w2;
    if (tail) *(short8*)&r[(768 + tid) * 8] = w3;
}

// ---------------------------------------------------------------------------
// Reduce bf16 split-K chunks -> BcatT[b][s][128+p]; split: [b][ch][s][p] bf16
// grid: 784 x 256 (thread per (b,s,p8))
// ---------------------------------------------------------------------------
__global__ void k_reduce_split(const ushort* __restrict__ splitb, ushort* __restrict__ BcatT) {
    long i = (long)blockIdx.x * 256 + threadIdx.x;   // over B_*S_*(P_/8)
    if (i >= (long)B_ * S_ * (P_ / 8)) return;
    int p8 = (int)(i & (P_ / 8 - 1));
    long sp = i >> 4;
    int b = (int)(sp / S_);
    long s = sp - (long)b * S_;
    const ushort* base = splitb + ((long)b * KS_ * S_ + s) * P_ + p8 * 8;
    float acc[8] = {0.f, 0.f, 0.f, 0.f, 0.f, 0.f, 0.f, 0.f};
    #pragma unroll
    for (int ch = 0; ch < KS_; ++ch) {
        short8 u = *(const short8*)&base[(long)ch * S_ * P_];
        #pragma unroll
        for (int j = 0; j < 8; ++j) acc[j] += bf2f((ushort)u[j]);
    }
    short8 w;
    #pragma unroll
    for (int j = 0; j < 8; ++j) w[j] = (short)f2bf(acc[j]);
    *(short8*)&BcatT[((long)b * S_ + s) * 256 + 128 + p8 * 8] = w;
}

// ---------------------------------------------------------------------------
// BN apply + residual: out += BN(y) using fused Stat accumulators;
// LDS-tiled transpose for xb_sc writes. grid: B_*98 x 256
// ---------------------------------------------------------------------------
__global__ __launch_bounds__(256)
void k_bn_apply(const float* __restrict__ y, const float* __restrict__ Stat,
                const float* __restrict__ gamma, const float* __restrict__ beta,
                float* __restrict__ out, ushort* __restrict__ xb_sc) {
    __shared__ ushort tl[64][TPAD];
    const int bs = blockIdx.x;
    const int b = bs / 98, s0 = (bs - b * 98) * 64;
    const int tid = threadIdx.x, sl = tid & 63, cg = tid >> 6;
    const float invn = 1.f / (float)(B_ * S_);
    #pragma unroll 4
    for (int it = 0; it < 64; ++it) {
        int c = it * 4 + cg;
        float m = Stat[c] * invn;
        float var = Stat[C_ + c] * invn - m * m;
        float rs = rsqrtf(var + EPS_);
        float sc = rs * gamma[c];
        float sh = beta[c] - m * sc;
        long idx = ((long)b * C_ + c) * S_ + s0 + sl;
        float v = out[idx] + y[idx] * sc + sh;
        out[idx] = v;
        tl[sl][c] = f2bf(v);
    }
    __syncthreads();
    ushort* xs = xb_sc + ((long)b * S_ + s0) * C_;
    #pragma unroll
    for (int u0 = 0; u0 < 2048; u0 += 256) {
        int u = u0 + tid;
        int s = u >> 5, c8 = (u & 31) << 3;
        short8 w = *(const short8*)&tl[s][c8];
        *(short8*)&xs[(long)s * C_ + c8] = w;
    }
}

// ---------------------------------------------------------------------------
extern "C" void kernel_launch(void* const* d_in, const int* in_sizes, int n_in,
                              void* d_out, int out_size, void* d_ws, size_t ws_size,
                              hipStream_t stream) {
    const float* x     = (const float*)d_in[0];
    const float* Wt    = (const float*)d_in[1];
    const float* Wp    = (const float*)d_in[2];
    const float* Wg    = (const float*)d_in[3];
    const float* W1    = (const float*)d_in[4];
    const float* W2    = (const float*)d_in[5];
    const float* gamma = (const float*)d_in[6];
    const float* beta  = (const float*)d_in[7];
    float* out = (float*)d_out;

    char* ws = (char*)d_ws;
    size_t off = 0;
    auto alloc = [&](size_t bytes) -> void* {
        void* p = ws + off;
        off = (off + bytes + 255) & ~(size_t)255;
        return p;
    };
    ushort* att    = (ushort*)alloc((size_t)B_ * S_ * S_ * 2);       // scores/att bf16
    ushort* tpb    = (ushort*)alloc((size_t)B_ * S_ * 256 * 2);      // [s][t | p^T]
    ushort* gTb    = (ushort*)alloc((size_t)B_ * P_ * S_ * 2);       // g^T [P,S]
    ushort* BcatT  = (ushort*)alloc((size_t)B_ * S_ * 256 * 2);      // [s][g | x2pre]
    ushort* xbsc   = (ushort*)alloc((size_t)B_ * S_ * C_ * 2);       // out^T bf16 [S,C]
    float*  y      = (float*)alloc((size_t)B_ * C_ * S_ * 4);        // x1+x2 fp32 [C,S]
    ushort* splitb = (ushort*)alloc((size_t)B_ * KS_ * S_ * P_ * 2); // split-K bf16
    ushort* Wtpb   = (ushort*)alloc((size_t)2 * P_ * C_ * 2);
    ushort* Wgb    = (ushort*)alloc((size_t)NS_ * P_ * C_ * 2);
    ushort* catb   = (ushort*)alloc((size_t)NS_ * C_ * 256 * 2);
    float*  statb  = (float*)alloc((size_t)NS_ * 2 * C_ * 4);
    if (off > ws_size) return;

    dim3 blk(256);

    k_convert_weights<<<1280, 256, 0, stream>>>(Wt, Wp, Wg, W1, W2, Wtpb, Wgb, catb, statb);
    k_init_x<<<B_ * 98, 256, 0, stream>>>(x, out, xbsc);

    // [t | p^T] = NT(xbsc[S,C], Wtp[256,C]) -> tpb [S,256]   (TM=64: 392 blocks)
    k_gemm<0, 64><<<dim3(S_ / 64, 2, B_), blk, 0, stream>>>(
        xbsc, Wtpb, tpb, nullptr, nullptr, S_, 256, C_, C_, C_, 256, 0,
        (long)S_ * C_, 0, (long)S_ * 256, 0, 0, 1, C_);
    // scores = NT(t[S,P] lda=256, p^T[S,P] ldb=256) -> att [S,S]
    k_gemm<0, 128><<<dim3(S_ / 128, S_ / 128, B_), blk, 0, stream>>>(
        tpb, tpb + 128, att, nullptr, nullptr, S_, S_, P_, 256, 256, S_, 0,
        (long)S_ * 256, (long)S_ * 256, (long)S_ * S_, 0, 0, 1, P_);
    k_softmax<<<B_ * S_, 256, 0, stream>>>(att);

    for (int i = 0; i < NS_; ++i) {
        // g = NT(xbsc, Wg[i]) -> BcatT cols [0,128) (ldo=256) + gTb [P,S]  (TM=64)
        k_gemm<1, 64><<<dim3(S_ / 64, 1, B_), blk, 0, stream>>>(
            xbsc, Wgb + (size_t)i * P_ * C_, BcatT, gTb, nullptr,
            S_, P_, C_, C_, C_, 256, S_,
            (long)S_ * C_, 0, (long)S_ * 256, 0, (long)P_ * S_, 1, C_);
        // x2pre(split-K) = NT(att[S,S], gT[P,S]) -> splitb bf16 [b][ch][S][P]
        k_gemm<0, 128><<<dim3(S_ / 128, 1, B_ * KS_), blk, 0, stream>>>(
            att, gTb, splitb, nullptr, nullptr, S_, P_, S_, S_, S_, P_, 0,
            (long)S_ * S_, (long)P_ * S_, (long)KS_ * S_ * P_, (long)S_ * P_, 0, KS_, KCH_);
        k_reduce_split<<<784, 256, 0, stream>>>(splitb, BcatT);
        // y = NT(cat[i][C,256], BcatT[S,256]) -> [C,S] fp32 + BN stats  (TM=64: 392)
        k_gemm<3, 64><<<dim3(C_ / 64, S_ / 128, B_), blk, 0, stream>>>(
            catb + (size_t)i * C_ * 256, BcatT, y, nullptr, statb + (size_t)i * 2 * C_,
            C_, S_, 256, 256, 256, S_, 0,
            0, (long)S_ * 256, (long)C_ * S_, 0, 0, 1, 256);
        k_bn_apply<<<B_ * 98, 256, 0, stream>>>(y, statb + (size_t)i * 2 * C_,
                                                gamma + i * C_, beta + i * C_, out, xbsc);
    }
}